// Round 1
// baseline (1114.256 us; speedup 1.0000x reference)
//
#include <hip/hip_runtime.h>
#include <hip/hip_bf16.h>

#define BB 8192
#define SS 20
#define DD 300
#define JJ 512
#define NII 1000
#define VGG 2078

// ---------------- kernel 0: valid / nonzero masks ----------------
__global__ __launch_bounds__(256) void k0_valid(const int* __restrict__ labels,
                                                float* __restrict__ valid,
                                                float* __restrict__ nonzero) {
    int b = blockIdx.x * blockDim.x + threadIdx.x;
    if (b >= BB) return;
    float v = 1.f;
    for (int s = 0; s < SS; ++s) {
        float nz = (labels[b * SS + s] != 0) ? 1.f : 0.f;
        v *= nz;
        nonzero[b * SS + s] = nz;
        valid[b * SS + s] = v;
    }
}

// ---------------- kernel 1: fea_emb = guide[ann[2b]] @ W_emb^T + b_emb ----------
// M=8192 (gathered), N=512, K=2078. BM=BN=64, BK=32, 256 thr, 4x4/thread.
__global__ __launch_bounds__(256) void k1_feaemb(const float* __restrict__ guide,
                                                 const int* __restrict__ ann,
                                                 const float* __restrict__ W_emb,
                                                 const float* __restrict__ b_emb,
                                                 float* __restrict__ fea_emb) {
    __shared__ float As[32][64];
    __shared__ float Bs[32][64];
    const int m0 = blockIdx.x * 64;
    const int n0 = blockIdx.y * 64;
    const int t = threadIdx.x;
    const int tx = t & 15, ty = t >> 4;

    // load mapping: each thread stages 8 consecutive k of one row
    const int lrow = t >> 2;          // t/4 : 0..63
    const int lk0 = (t & 3) * 8;      // 0,8,16,24
    const long grow = (long)ann[2 * (m0 + lrow)];   // gathered guide row
    const long brow = (long)(n0 + lrow);

    float acc[4][4] = {};

    for (int kt = 0; kt < VGG; kt += 32) {
#pragma unroll
        for (int u = 0; u < 8; ++u) {
            int kk = kt + lk0 + u;
            As[lk0 + u][lrow] = (kk < VGG) ? guide[grow * VGG + kk] : 0.f;
            Bs[lk0 + u][lrow] = (kk < VGG) ? W_emb[brow * VGG + kk] : 0.f;
        }
        __syncthreads();
#pragma unroll
        for (int k = 0; k < 32; ++k) {
            float4 a4 = *(const float4*)&As[k][ty * 4];
            float4 b4 = *(const float4*)&Bs[k][tx * 4];
            float a[4] = {a4.x, a4.y, a4.z, a4.w};
            float bv[4] = {b4.x, b4.y, b4.z, b4.w};
#pragma unroll
            for (int i = 0; i < 4; ++i)
#pragma unroll
                for (int j = 0; j < 4; ++j) acc[i][j] += a[i] * bv[j];
        }
        __syncthreads();
    }
#pragma unroll
    for (int i = 0; i < 4; ++i) {
        int m = m0 + ty * 4 + i;
#pragma unroll
        for (int j = 0; j < 4; ++j) {
            int n = n0 + tx * 4 + j;
            fea_emb[(long)m * JJ + n] = acc[i][j] + b_emb[n];
        }
    }
}

// ---------------- kernel 2: fused cxt_emb GEMM + tanh + w_fc reduce -> scores ---
// M = B*S = 163840 rows (m = b*S+s), N=J=512 (loop 8x64), K=D=300 (15x20).
__global__ __launch_bounds__(256) void k2_scores(const float* __restrict__ context,
                                                 const float* __restrict__ W_sent,
                                                 const float* __restrict__ b_sent,
                                                 const float* __restrict__ w_fc,
                                                 const float* __restrict__ b_fc,
                                                 const float* __restrict__ fea_emb,
                                                 const float* __restrict__ b_emb,
                                                 const float* __restrict__ valid,
                                                 float* __restrict__ scores) {
    __shared__ float As[20][64];
    __shared__ float Bs[20][64];
    __shared__ float red[64][17];
    const int m0 = blockIdx.x * 64;
    const int t = threadIdx.x;
    const int tx = t & 15, ty = t >> 4;

    const int lrow = t >> 2;          // t/4 : 0..63
    const int lk0 = (t & 3) * 5;      // 0,5,10,15

    float sp[4] = {0.f, 0.f, 0.f, 0.f};

    for (int jt = 0; jt < JJ; jt += 64) {
        float acc[4][4] = {};
        for (int kt = 0; kt < DD; kt += 20) {
#pragma unroll
            for (int u = 0; u < 5; ++u) {
                As[lk0 + u][lrow] = context[(long)(m0 + lrow) * DD + kt + lk0 + u];
                Bs[lk0 + u][lrow] = W_sent[(long)(jt + lrow) * DD + kt + lk0 + u];
            }
            __syncthreads();
#pragma unroll
            for (int k = 0; k < 20; ++k) {
                float4 a4 = *(const float4*)&As[k][ty * 4];
                float4 b4 = *(const float4*)&Bs[k][tx * 4];
                float a[4] = {a4.x, a4.y, a4.z, a4.w};
                float bv[4] = {b4.x, b4.y, b4.z, b4.w};
#pragma unroll
                for (int i = 0; i < 4; ++i)
#pragma unroll
                    for (int j = 0; j < 4; ++j) acc[i][j] += a[i] * bv[j];
            }
            __syncthreads();
        }
        // epilogue: tanh + guid + w_fc partial reduce (registers only)
#pragma unroll
        for (int i = 0; i < 4; ++i) {
            int m = m0 + ty * 4 + i;
            int b = m / SS;
            float vld = valid[m];
#pragma unroll
            for (int j = 0; j < 4; ++j) {
                int n = jt + tx * 4 + j;
                float guid = (vld != 0.f) ? fea_emb[(long)b * JJ + n] : b_emb[n];
                float h = tanhf(acc[i][j] + b_sent[n] + guid);
                sp[i] += h * w_fc[n];
            }
        }
    }
    // reduce partial scores across the 16 tx lanes per row
#pragma unroll
    for (int i = 0; i < 4; ++i) red[ty * 4 + i][tx] = sp[i];
    __syncthreads();
    if (t < 64) {
        float s = 0.f;
#pragma unroll
        for (int x = 0; x < 16; ++x) s += red[t][x];
        scores[m0 + t] = s + b_fc[0];
    }
}

// ---------------- kernel 3: softmax + mask + renorm + weighted sum -------------
__global__ __launch_bounds__(256) void k3_out(const float* __restrict__ scores,
                                              const float* __restrict__ nonzero,
                                              const float* __restrict__ embedded,
                                              float* __restrict__ out) {
    __shared__ float w[SS];
    const int b = blockIdx.x;
    const int t = threadIdx.x;
    if (t == 0) {
        float sc[SS], nz[SS];
        float mx = -1e30f;
        for (int s = 0; s < SS; ++s) {
            sc[s] = scores[b * SS + s];
            nz[s] = nonzero[b * SS + s];
            mx = fmaxf(mx, sc[s]);
        }
        float den = 0.f;
        float e[SS];
        for (int s = 0; s < SS; ++s) {
            e[s] = nz[s] * expf(sc[s] - mx);
            den += e[s];
        }
        float inv = 1.f / den;
        for (int s = 0; s < SS; ++s) w[s] = e[s] * inv;
    }
    __syncthreads();
    for (int d = t; d < DD; d += 256) {
        float acc = 0.f;
#pragma unroll
        for (int s = 0; s < SS; ++s)
            acc += w[s] * embedded[((long)b * SS + s) * DD + d];
        out[(long)b * DD + d] = acc;
    }
}

extern "C" void kernel_launch(void* const* d_in, const int* in_sizes, int n_in,
                              void* d_out, int out_size, void* d_ws, size_t ws_size,
                              hipStream_t stream) {
    const float* context  = (const float*)d_in[0];
    const float* embedded = (const float*)d_in[1];
    const int*   labels   = (const int*)d_in[2];
    const float* guide    = (const float*)d_in[3];
    const int*   ann      = (const int*)d_in[4];
    const float* W_sent   = (const float*)d_in[5];
    const float* b_sent   = (const float*)d_in[6];
    const float* W_emb    = (const float*)d_in[7];
    const float* b_emb    = (const float*)d_in[8];
    const float* w_fc     = (const float*)d_in[9];
    const float* b_fc     = (const float*)d_in[10];
    float* out = (float*)d_out;

    float* ws      = (float*)d_ws;
    float* fea_emb = ws;                              // B*J
    float* valid   = fea_emb + (size_t)BB * JJ;       // B*S
    float* nonzero = valid + (size_t)BB * SS;         // B*S
    float* scores  = nonzero + (size_t)BB * SS;       // B*S

    hipLaunchKernelGGL(k0_valid, dim3(BB / 256), dim3(256), 0, stream,
                       labels, valid, nonzero);
    hipLaunchKernelGGL(k1_feaemb, dim3(BB / 64, JJ / 64), dim3(256), 0, stream,
                       guide, ann, W_emb, b_emb, fea_emb);
    hipLaunchKernelGGL(k2_scores, dim3((BB * SS) / 64), dim3(256), 0, stream,
                       context, W_sent, b_sent, w_fc, b_fc, fea_emb, b_emb, valid,
                       scores);
    hipLaunchKernelGGL(k3_out, dim3(BB), dim3(256), 0, stream,
                       scores, nonzero, embedded, out);
}

// Round 2
// 417.444 us; speedup vs baseline: 2.6692x; 2.6692x over previous
//
#include <hip/hip_runtime.h>
#include <hip/hip_bf16.h>

#define BB 8192
#define SS 20
#define DD 300
#define JJ 512
#define NII 1000
#define VGG 2078
#define KP2 328   // k2 A-lds row stride (bf16 elems): 656B, 16B-aligned, bank-tiled
#define BP1 72    // 64x64 chunk lds row stride: 144B, 16B-aligned, bank-tiled

typedef __attribute__((ext_vector_type(8))) short short8v;
typedef __attribute__((ext_vector_type(4))) float float4v;

__device__ __forceinline__ float tanh_fast(float x) {
    float xx = fminf(fmaxf(x, -15.f), 15.f);
    float e = __expf(2.f * xx);
    return (e - 1.f) / (e + 1.f);
}

// ---------------- pad+convert fp32 -> bf16 with zero pad on cols ----------------
__global__ __launch_bounds__(256) void kc_pad_bf16(const float* __restrict__ src,
                                                   __hip_bfloat16* __restrict__ dst,
                                                   int rows, int scols, int dcols) {
    int idx = blockIdx.x * 256 + threadIdx.x;
    if (idx >= rows * dcols) return;
    int r = idx / dcols, c = idx % dcols;
    float v = (c < scols) ? src[(long)r * scols + c] : 0.f;
    dst[idx] = __float2bfloat16(v);
}

// ---------------- kernel 0: valid / nonzero masks ----------------
__global__ __launch_bounds__(256) void k0_valid(const int* __restrict__ labels,
                                                float* __restrict__ valid,
                                                float* __restrict__ nonzero) {
    int b = blockIdx.x * blockDim.x + threadIdx.x;
    if (b >= BB) return;
    float v = 1.f;
    for (int s = 0; s < SS; ++s) {
        float nz = (labels[b * SS + s] != 0) ? 1.f : 0.f;
        v *= nz;
        nonzero[b * SS + s] = nz;
        valid[b * SS + s] = v;
    }
}

// ---------------- kernel 1 (MFMA): fea = bf16(guide[ann[2m]] @ W_emb^T + b_emb) --
// M=8192, N=512, K=2078 (padded 2112 = 33*64). BM=BN=64, 4 waves 2x2.
__global__ __launch_bounds__(256) void k1_feaemb_mfma(
    const __hip_bfloat16* __restrict__ Gb,   // [NII][2112]
    const int* __restrict__ ann,
    const __hip_bfloat16* __restrict__ Web,  // [JJ][2112]
    const float* __restrict__ b_emb,
    __hip_bfloat16* __restrict__ fea) {      // [BB][JJ]
    __shared__ __hip_bfloat16 Al[64 * BP1];
    __shared__ __hip_bfloat16 Bl[64 * BP1];
    __shared__ int sann[64];
    const int t = threadIdx.x;
    const int m0 = blockIdx.x * 64;
    const int n0 = blockIdx.y * 64;
    const int lane = t & 63;
    const int w = t >> 6;
    const int wm = w >> 1, wn = w & 1;
    const int li = lane & 15, lq = lane >> 4;

    if (t < 64) sann[t] = ann[2 * (m0 + t)];
    __syncthreads();

    float4v acc[2][2] = {};

    for (int kt = 0; kt < 33; ++kt) {
        for (int c = t; c < 512; c += 256) {
            int rr = c >> 3, off = (c & 7) * 8;
            *(uint4*)&Al[rr * BP1 + off] =
                *(const uint4*)(Gb + (long)sann[rr] * 2112 + kt * 64 + off);
            *(uint4*)&Bl[rr * BP1 + off] =
                *(const uint4*)(Web + (long)(n0 + rr) * 2112 + kt * 64 + off);
        }
        __syncthreads();
#pragma unroll
        for (int ks = 0; ks < 2; ++ks) {
            short8v a[2], b[2];
#pragma unroll
            for (int mt = 0; mt < 2; ++mt)
                a[mt] = *(const short8v*)&Al[(wm * 32 + mt * 16 + li) * BP1 + ks * 32 + lq * 8];
#pragma unroll
            for (int nt = 0; nt < 2; ++nt)
                b[nt] = *(const short8v*)&Bl[(wn * 32 + nt * 16 + li) * BP1 + ks * 32 + lq * 8];
#pragma unroll
            for (int mt = 0; mt < 2; ++mt)
#pragma unroll
                for (int nt = 0; nt < 2; ++nt)
                    acc[mt][nt] = __builtin_amdgcn_mfma_f32_16x16x32_bf16(
                        a[mt], b[nt], acc[mt][nt], 0, 0, 0);
        }
        __syncthreads();
    }
#pragma unroll
    for (int nt = 0; nt < 2; ++nt) {
        int col = n0 + wn * 32 + nt * 16 + li;
        float be = b_emb[col];
#pragma unroll
        for (int mt = 0; mt < 2; ++mt)
#pragma unroll
            for (int reg = 0; reg < 4; ++reg) {
                int row = wm * 32 + mt * 16 + lq * 4 + reg;
                fea[(long)(m0 + row) * JJ + col] = __float2bfloat16(acc[mt][nt][reg] + be);
            }
    }
}

// ---------------- kernel 2 (MFMA): fused scores -------------------------------
// M=B*S=163840, N=512 (8 jt tiles), K=300 (padded 320). BM=64, A panel resident.
__global__ __launch_bounds__(256) void k2_scores_mfma(
    const float* __restrict__ context,
    const __hip_bfloat16* __restrict__ Wsb,  // [JJ][320]
    const float* __restrict__ b_sent,
    const float* __restrict__ w_fc,
    const float* __restrict__ b_fc,
    const __hip_bfloat16* __restrict__ fea,  // [BB][JJ]
    const float* __restrict__ b_emb,
    const float* __restrict__ valid,
    float* __restrict__ scores) {
    __shared__ __hip_bfloat16 Al[64 * KP2];
    __shared__ __hip_bfloat16 Bl[2][64 * BP1];
    __shared__ float red[2][64];
    const int t = threadIdx.x;
    const int m0 = blockIdx.x * 64;
    const int lane = t & 63;
    const int w = t >> 6;
    const int wm = w >> 1, wn = w & 1;
    const int li = lane & 15, lq = lane >> 4;

    // stage A: 64 rows x 300 f32 -> bf16, then zero-pad k in [300,320)
    for (int idx = t; idx < 64 * 75; idx += 256) {
        int r = idx / 75, q = idx % 75;
        float4 v = *(const float4*)(context + (long)(m0 + r) * DD + q * 4);
        __hip_bfloat16 h0 = __float2bfloat16(v.x), h1 = __float2bfloat16(v.y);
        __hip_bfloat16 h2 = __float2bfloat16(v.z), h3 = __float2bfloat16(v.w);
        ushort4 pk;
        pk.x = *(unsigned short*)&h0; pk.y = *(unsigned short*)&h1;
        pk.z = *(unsigned short*)&h2; pk.w = *(unsigned short*)&h3;
        *(ushort4*)&Al[r * KP2 + q * 4] = pk;
    }
    for (int idx = t; idx < 64 * 5; idx += 256) {
        int r = idx / 5, q = idx % 5;
        ushort4 z; z.x = z.y = z.z = z.w = 0;
        *(ushort4*)&Al[r * KP2 + 300 + q * 4] = z;
    }

    // hoist per-row-slot metadata
    int bb[8]; float vld[8];
#pragma unroll
    for (int mt = 0; mt < 2; ++mt)
#pragma unroll
        for (int reg = 0; reg < 4; ++reg) {
            int m = m0 + wm * 32 + mt * 16 + lq * 4 + reg;
            bb[mt * 4 + reg] = m / SS;
            vld[mt * 4 + reg] = valid[m];
        }
    float sp[8] = {0.f, 0.f, 0.f, 0.f, 0.f, 0.f, 0.f, 0.f};
    const float bfc = b_fc[0];

    for (int jt = 0; jt < JJ; jt += 64) {
        float4v acc[2][2] = {};
        for (int kt = 0; kt < 5; ++kt) {
            int buf = kt & 1;
            for (int c = t; c < 512; c += 256) {
                int rr = c >> 3, off = (c & 7) * 8;
                *(uint4*)&Bl[buf][rr * BP1 + off] =
                    *(const uint4*)(Wsb + (long)(jt + rr) * 320 + kt * 64 + off);
            }
            __syncthreads();
#pragma unroll
            for (int ks = 0; ks < 2; ++ks) {
                short8v a[2], b[2];
#pragma unroll
                for (int mt = 0; mt < 2; ++mt)
                    a[mt] = *(const short8v*)&Al[(wm * 32 + mt * 16 + li) * KP2 +
                                                 kt * 64 + ks * 32 + lq * 8];
#pragma unroll
                for (int nt = 0; nt < 2; ++nt)
                    b[nt] = *(const short8v*)&Bl[buf][(wn * 32 + nt * 16 + li) * BP1 +
                                                      ks * 32 + lq * 8];
#pragma unroll
                for (int mt = 0; mt < 2; ++mt)
#pragma unroll
                    for (int nt = 0; nt < 2; ++nt)
                        acc[mt][nt] = __builtin_amdgcn_mfma_f32_16x16x32_bf16(
                            a[mt], b[nt], acc[mt][nt], 0, 0, 0);
            }
            __syncthreads();
        }
        // fused epilogue: tanh + w_fc partial reduction (registers only)
#pragma unroll
        for (int nt = 0; nt < 2; ++nt) {
            int col = jt + wn * 32 + nt * 16 + li;
            float bs = b_sent[col], wf = w_fc[col], be = b_emb[col];
#pragma unroll
            for (int mt = 0; mt < 2; ++mt)
#pragma unroll
                for (int reg = 0; reg < 4; ++reg) {
                    int slot = mt * 4 + reg;
                    float guid = (vld[slot] != 0.f)
                                     ? __bfloat162float(fea[(long)bb[slot] * JJ + col])
                                     : be;
                    float h = tanh_fast(acc[mt][nt][reg] + bs + guid);
                    sp[slot] += h * wf;
                }
        }
    }
    // reduce across 16 lanes (cols) per row-slot
#pragma unroll
    for (int slot = 0; slot < 8; ++slot) {
        float v = sp[slot];
        v += __shfl_xor(v, 1); v += __shfl_xor(v, 2);
        v += __shfl_xor(v, 4); v += __shfl_xor(v, 8);
        sp[slot] = v;
    }
    if (li == 0) {
#pragma unroll
        for (int mt = 0; mt < 2; ++mt)
#pragma unroll
            for (int reg = 0; reg < 4; ++reg)
                red[wn][wm * 32 + mt * 16 + lq * 4 + reg] = sp[mt * 4 + reg];
    }
    __syncthreads();
    if (t < 64) scores[m0 + t] = red[0][t] + red[1][t] + bfc;
}

// ---------------- kernel 3: softmax + mask + renorm + weighted sum -------------
__global__ __launch_bounds__(256) void k3_out(const float* __restrict__ scores,
                                              const float* __restrict__ nonzero,
                                              const float* __restrict__ embedded,
                                              float* __restrict__ out) {
    __shared__ float wgt[SS];
    const int b = blockIdx.x;
    const int t = threadIdx.x;
    if (t == 0) {
        float sc[SS], nz[SS];
        float mx = -1e30f;
        for (int s = 0; s < SS; ++s) {
            sc[s] = scores[b * SS + s];
            nz[s] = nonzero[b * SS + s];
            mx = fmaxf(mx, sc[s]);
        }
        float den = 0.f;
        float e[SS];
        for (int s = 0; s < SS; ++s) {
            e[s] = nz[s] * expf(sc[s] - mx);
            den += e[s];
        }
        float inv = 1.f / den;
        for (int s = 0; s < SS; ++s) wgt[s] = e[s] * inv;
    }
    __syncthreads();
    for (int d = t; d < DD; d += 256) {
        float acc = 0.f;
#pragma unroll
        for (int s = 0; s < SS; ++s)
            acc += wgt[s] * embedded[((long)b * SS + s) * DD + d];
        out[(long)b * DD + d] = acc;
    }
}

extern "C" void kernel_launch(void* const* d_in, const int* in_sizes, int n_in,
                              void* d_out, int out_size, void* d_ws, size_t ws_size,
                              hipStream_t stream) {
    const float* context  = (const float*)d_in[0];
    const float* embedded = (const float*)d_in[1];
    const int*   labels   = (const int*)d_in[2];
    const float* guide    = (const float*)d_in[3];
    const int*   ann      = (const int*)d_in[4];
    const float* W_sent   = (const float*)d_in[5];
    const float* b_sent   = (const float*)d_in[6];
    const float* W_emb    = (const float*)d_in[7];
    const float* b_emb    = (const float*)d_in[8];
    const float* w_fc     = (const float*)d_in[9];
    const float* b_fc     = (const float*)d_in[10];
    float* out = (float*)d_out;

    char* w = (char*)d_ws;
    __hip_bfloat16* fea   = (__hip_bfloat16*)(w);              // 8192*512*2  = 8388608
    float* valid          = (float*)(w + 8388608);             // 655360
    float* nonzero        = (float*)(w + 9043968);             // 655360
    float* scores         = (float*)(w + 9699328);             // 655360
    __hip_bfloat16* Wsb   = (__hip_bfloat16*)(w + 10354688);   // 512*320*2   = 327680
    __hip_bfloat16* Web   = (__hip_bfloat16*)(w + 10682368);   // 512*2112*2  = 2162688
    __hip_bfloat16* Gb    = (__hip_bfloat16*)(w + 12845056);   // 1000*2112*2 = 4224000
    // total 17069056 bytes

    hipLaunchKernelGGL(kc_pad_bf16, dim3((JJ * 320 + 255) / 256), dim3(256), 0, stream,
                       W_sent, Wsb, JJ, DD, 320);
    hipLaunchKernelGGL(kc_pad_bf16, dim3((JJ * 2112 + 255) / 256), dim3(256), 0, stream,
                       W_emb, Web, JJ, VGG, 2112);
    hipLaunchKernelGGL(kc_pad_bf16, dim3((NII * 2112 + 255) / 256), dim3(256), 0, stream,
                       guide, Gb, NII, VGG, 2112);
    hipLaunchKernelGGL(k0_valid, dim3(BB / 256), dim3(256), 0, stream,
                       labels, valid, nonzero);
    hipLaunchKernelGGL(k1_feaemb_mfma, dim3(BB / 64, JJ / 64), dim3(256), 0, stream,
                       Gb, ann, Web, b_emb, fea);
    hipLaunchKernelGGL(k2_scores_mfma, dim3((BB * SS) / 64), dim3(256), 0, stream,
                       context, Wsb, b_sent, w_fc, b_fc, fea, b_emb, valid, scores);
    hipLaunchKernelGGL(k3_out, dim3(BB), dim3(256), 0, stream,
                       scores, nonzero, embedded, out);
}

// Round 3
// 316.946 us; speedup vs baseline: 3.5156x; 1.3171x over previous
//
#include <hip/hip_runtime.h>
#include <hip/hip_bf16.h>

#define BB 8192
#define SS 20
#define DD 300
#define JJ 512
#define NII 1000
#define VGG 2078
#define KP 320          // k2 K padded (10 k-steps of 32)
#define RB 640          // k2 LDS row bytes = KP*2
#define BP1 72          // k1 64x64 chunk lds row stride

typedef __attribute__((ext_vector_type(8))) short short8v;
typedef __attribute__((ext_vector_type(4))) float float4v;

__device__ __forceinline__ float tanh_fast(float x) {
    float xx = fminf(fmaxf(x, -15.f), 15.f);
    float e = __expf(2.f * xx);
    return (e - 1.f) * __builtin_amdgcn_rcpf(e + 1.f);
}

__device__ __forceinline__ unsigned short bf16u(float x) {
    __hip_bfloat16 h = __float2bfloat16(x);
    return *(unsigned short*)&h;
}

// ---------------- pad+convert fp32 -> bf16 with zero pad on cols ----------------
__global__ __launch_bounds__(256) void kc_pad_bf16(const float* __restrict__ src,
                                                   __hip_bfloat16* __restrict__ dst,
                                                   int rows, int scols, int dcols) {
    int idx = blockIdx.x * 256 + threadIdx.x;
    if (idx >= rows * dcols) return;
    int r = idx / dcols, c = idx % dcols;
    float v = (c < scols) ? src[(long)r * scols + c] : 0.f;
    dst[idx] = __float2bfloat16(v);
}

// ---------------- kernel 0: valid / nonzero masks ----------------
__global__ __launch_bounds__(256) void k0_valid(const int* __restrict__ labels,
                                                float* __restrict__ valid,
                                                float* __restrict__ nonzero) {
    int b = blockIdx.x * blockDim.x + threadIdx.x;
    if (b >= BB) return;
    float v = 1.f;
    for (int s = 0; s < SS; ++s) {
        float nz = (labels[b * SS + s] != 0) ? 1.f : 0.f;
        v *= nz;
        nonzero[b * SS + s] = nz;
        valid[b * SS + s] = v;
    }
}

// ---------------- kernel 1 (MFMA): femb = bf16(guide @ W_emb^T + b_emb) --------
// M=1000 (pad 1024), N=512, K=2112. BM=BN=64, 4 waves 2x2.
__global__ __launch_bounds__(256) void k1_femb_mfma(
    const __hip_bfloat16* __restrict__ Gb,   // [NII][2112]
    const __hip_bfloat16* __restrict__ Web,  // [JJ][2112]
    const float* __restrict__ b_emb,
    __hip_bfloat16* __restrict__ femb) {     // [1024][JJ]
    __shared__ __hip_bfloat16 Al[64 * BP1];
    __shared__ __hip_bfloat16 Bl[64 * BP1];
    const int t = threadIdx.x;
    const int m0 = blockIdx.x * 64;
    const int n0 = blockIdx.y * 64;
    const int lane = t & 63;
    const int w = t >> 6;
    const int wm = w >> 1, wn = w & 1;
    const int li = lane & 15, lq = lane >> 4;

    float4v acc[2][2] = {};

    for (int kt = 0; kt < 33; ++kt) {
        for (int c = t; c < 512; c += 256) {
            int rr = c >> 3, off = (c & 7) * 8;
            int gr = m0 + rr; if (gr > NII - 1) gr = NII - 1;
            *(uint4*)&Al[rr * BP1 + off] =
                *(const uint4*)(Gb + (long)gr * 2112 + kt * 64 + off);
            *(uint4*)&Bl[rr * BP1 + off] =
                *(const uint4*)(Web + (long)(n0 + rr) * 2112 + kt * 64 + off);
        }
        __syncthreads();
#pragma unroll
        for (int ks = 0; ks < 2; ++ks) {
            short8v a[2], b[2];
#pragma unroll
            for (int mt = 0; mt < 2; ++mt)
                a[mt] = *(const short8v*)&Al[(wm * 32 + mt * 16 + li) * BP1 + ks * 32 + lq * 8];
#pragma unroll
            for (int nt = 0; nt < 2; ++nt)
                b[nt] = *(const short8v*)&Bl[(wn * 32 + nt * 16 + li) * BP1 + ks * 32 + lq * 8];
#pragma unroll
            for (int mt = 0; mt < 2; ++mt)
#pragma unroll
                for (int nt = 0; nt < 2; ++nt)
                    acc[mt][nt] = __builtin_amdgcn_mfma_f32_16x16x32_bf16(
                        a[mt], b[nt], acc[mt][nt], 0, 0, 0);
        }
        __syncthreads();
    }
#pragma unroll
    for (int nt = 0; nt < 2; ++nt) {
        int col = n0 + wn * 32 + nt * 16 + li;
        float be = b_emb[col];
#pragma unroll
        for (int mt = 0; mt < 2; ++mt)
#pragma unroll
            for (int reg = 0; reg < 4; ++reg) {
                int row = wm * 32 + mt * 16 + lq * 4 + reg;
                femb[(long)(m0 + row) * JJ + col] = __float2bfloat16(acc[mt][nt][reg] + be);
            }
    }
}

// ---------------- kernel 2 (MFMA): fused scores -------------------------------
__global__ __launch_bounds__(256, 2) void k2_scores_mfma(
    const float* __restrict__ context,
    const __hip_bfloat16* __restrict__ Wsb,  // [JJ][KP]
    const float* __restrict__ b_sent,
    const float* __restrict__ w_fc,
    const float* __restrict__ b_fc,
    const __hip_bfloat16* __restrict__ femb, // [1024][JJ]
    const int* __restrict__ ann,
    const float* __restrict__ b_emb,
    const float* __restrict__ valid,
    float* __restrict__ scores) {
    __shared__ __hip_bfloat16 Bl[2][64 * KP];   // 81920 B exactly
    const int t = threadIdx.x;
    const int m0 = blockIdx.x * 64;
    const int lane = t & 63;
    const int w = t >> 6;
    const int wm = w >> 1, wn = w & 1;
    const int li = lane & 15, lq = lane >> 4;
    char* lds0 = (char*)&Bl[0][0];
    char* lds1 = (char*)&Bl[1][0];

    // ---- stage A (context f32 -> bf16, XOR-swizzled) into Bl[0] ----
    for (int idx = t; idx < 64 * 80; idx += 256) {
        int r = idx / 80, q = idx - (idx / 80) * 80;
        ushort4 pk;
        if (q < 75) {
            float4 v = *(const float4*)(context + (long)(m0 + r) * DD + q * 4);
            pk.x = bf16u(v.x); pk.y = bf16u(v.y); pk.z = bf16u(v.z); pk.w = bf16u(v.w);
        } else { pk.x = pk.y = pk.z = pk.w = 0; }
        int blk = (q >> 1) ^ (r & 7);
        *(ushort4*)(lds0 + r * RB + (blk << 4) + ((q & 1) << 3)) = pk;
    }

    // ---- per-row-slot metadata ----
    int gg[8]; float vv[8];
#pragma unroll
    for (int mt = 0; mt < 2; ++mt)
#pragma unroll
        for (int reg = 0; reg < 4; ++reg) {
            int m = m0 + wm * 32 + mt * 16 + lq * 4 + reg;
            int b = m / SS;
            gg[mt * 4 + reg] = ann[2 * b];
            vv[mt * 4 + reg] = valid[m];
        }
    __syncthreads();

    // ---- A fragments -> registers ----
    short8v areg[2][10];
#pragma unroll
    for (int mt = 0; mt < 2; ++mt) {
        int r = wm * 32 + mt * 16 + li;
#pragma unroll
        for (int kt = 0; kt < 10; ++kt) {
            int blk = (kt * 4 + lq) ^ (r & 7);
            areg[mt][kt] = *(const short8v*)(lds0 + r * RB + (blk << 4));
        }
    }
    __syncthreads();

    // ---- stage B tile jt=0 into Bl[0] ----
    {
        uint4 st[10];
#pragma unroll
        for (int i = 0; i < 10; ++i) {
            int c = i * 256 + t; int r = c / 40, c16 = c - r * 40;
            st[i] = *(const uint4*)(Wsb + (long)r * KP + c16 * 8);
        }
#pragma unroll
        for (int i = 0; i < 10; ++i) {
            int c = i * 256 + t; int r = c / 40, c16 = c - r * 40;
            int blk = c16 ^ (r & 7);
            *(uint4*)(lds0 + r * RB + (blk << 4)) = st[i];
        }
    }
    float sp[8] = {0.f, 0.f, 0.f, 0.f, 0.f, 0.f, 0.f, 0.f};
    __syncthreads();

    for (int jt = 0; jt < 8; ++jt) {
        char* cur = (jt & 1) ? lds1 : lds0;
        char* nxt = (jt & 1) ? lds0 : lds1;

        uint4 st[10];
        if (jt < 7) {
#pragma unroll
            for (int i = 0; i < 10; ++i) {
                int c = i * 256 + t; int r = c / 40, c16 = c - r * 40;
                st[i] = *(const uint4*)(Wsb + (long)((jt + 1) * 64 + r) * KP + c16 * 8);
            }
        }

        float4v acc[2][2] = {};
        const int rb0 = wn * 32 + li;
#pragma unroll
        for (int kt = 0; kt < 10; ++kt) {
            int blk = (kt * 4 + lq) ^ (li & 7);
            short8v b0 = *(const short8v*)(cur + rb0 * RB + (blk << 4));
            short8v b1 = *(const short8v*)(cur + (rb0 + 16) * RB + (blk << 4));
            acc[0][0] = __builtin_amdgcn_mfma_f32_16x16x32_bf16(areg[0][kt], b0, acc[0][0], 0, 0, 0);
            acc[0][1] = __builtin_amdgcn_mfma_f32_16x16x32_bf16(areg[0][kt], b1, acc[0][1], 0, 0, 0);
            acc[1][0] = __builtin_amdgcn_mfma_f32_16x16x32_bf16(areg[1][kt], b0, acc[1][0], 0, 0, 0);
            acc[1][1] = __builtin_amdgcn_mfma_f32_16x16x32_bf16(areg[1][kt], b1, acc[1][1], 0, 0, 0);
        }

        // fused epilogue: tanh + w_fc partial reduction
#pragma unroll
        for (int nt = 0; nt < 2; ++nt) {
            int col = jt * 64 + wn * 32 + nt * 16 + li;
            float bs = b_sent[col], wf = w_fc[col], be = b_emb[col];
#pragma unroll
            for (int mt = 0; mt < 2; ++mt)
#pragma unroll
                for (int reg = 0; reg < 4; ++reg) {
                    int slot = mt * 4 + reg;
                    float fv = __bfloat162float(femb[(long)gg[slot] * JJ + col]);
                    float guid = (vv[slot] != 0.f) ? fv : be;
                    sp[slot] += tanh_fast(acc[mt][nt][reg] + bs + guid) * wf;
                }
        }

        if (jt < 7) {
#pragma unroll
            for (int i = 0; i < 10; ++i) {
                int c = i * 256 + t; int r = c / 40, c16 = c - r * 40;
                int blk = c16 ^ (r & 7);
                *(uint4*)(nxt + r * RB + (blk << 4)) = st[i];
            }
        }
        __syncthreads();
    }

#pragma unroll
    for (int slot = 0; slot < 8; ++slot) {
        float v = sp[slot];
        v += __shfl_xor(v, 1); v += __shfl_xor(v, 2);
        v += __shfl_xor(v, 4); v += __shfl_xor(v, 8);
        sp[slot] = v;
    }
    float* red = (float*)lds0;   // Bl[0] free (last jt read Bl[1])
    if (li == 0) {
#pragma unroll
        for (int mt = 0; mt < 2; ++mt)
#pragma unroll
            for (int reg = 0; reg < 4; ++reg)
                red[wn * 64 + wm * 32 + mt * 16 + lq * 4 + reg] = sp[mt * 4 + reg];
    }
    __syncthreads();
    if (t < 64) scores[m0 + t] = red[t] + red[64 + t] + b_fc[0];
}

// ---------------- kernel 3: softmax + mask + renorm + weighted sum -------------
__global__ __launch_bounds__(256) void k3_out(const float* __restrict__ scores,
                                              const float* __restrict__ nonzero,
                                              const float* __restrict__ embedded,
                                              float* __restrict__ out) {
    __shared__ float wgt[3][SS];
    const int b0 = blockIdx.x * 3;
    const int t = threadIdx.x;
    if (t < 3) {
        int b = b0 + t;
        if (b < BB) {
            float sc[SS], nz[SS];
            float mx = -1e30f;
            for (int s = 0; s < SS; ++s) {
                sc[s] = scores[b * SS + s];
                nz[s] = nonzero[b * SS + s];
                mx = fmaxf(mx, sc[s]);
            }
            float den = 0.f, e[SS];
            for (int s = 0; s < SS; ++s) { e[s] = nz[s] * __expf(sc[s] - mx); den += e[s]; }
            float inv = 1.f / den;
            for (int s = 0; s < SS; ++s) wgt[t][s] = e[s] * inv;
        }
    }
    __syncthreads();
    if (t < 225) {
        int r = t / 75, q = t - r * 75;
        int b = b0 + r;
        if (b < BB) {
            float4 a; a.x = a.y = a.z = a.w = 0.f;
#pragma unroll
            for (int s = 0; s < SS; ++s) {
                float4 e = *(const float4*)(embedded + ((long)b * SS + s) * DD + q * 4);
                float ww = wgt[r][s];
                a.x += ww * e.x; a.y += ww * e.y; a.z += ww * e.z; a.w += ww * e.w;
            }
            *(float4*)(out + (long)b * DD + q * 4) = a;
        }
    }
}

extern "C" void kernel_launch(void* const* d_in, const int* in_sizes, int n_in,
                              void* d_out, int out_size, void* d_ws, size_t ws_size,
                              hipStream_t stream) {
    const float* context  = (const float*)d_in[0];
    const float* embedded = (const float*)d_in[1];
    const int*   labels   = (const int*)d_in[2];
    const float* guide    = (const float*)d_in[3];
    const int*   ann      = (const int*)d_in[4];
    const float* W_sent   = (const float*)d_in[5];
    const float* b_sent   = (const float*)d_in[6];
    const float* W_emb    = (const float*)d_in[7];
    const float* b_emb    = (const float*)d_in[8];
    const float* w_fc     = (const float*)d_in[9];
    const float* b_fc     = (const float*)d_in[10];
    float* out = (float*)d_out;

    char* w = (char*)d_ws;
    __hip_bfloat16* femb = (__hip_bfloat16*)(w);               // 1024*512*2 = 1048576
    float* valid         = (float*)(w + 1048576);
    float* nonzero       = (float*)(w + 1703936);
    float* scores        = (float*)(w + 2359296);
    __hip_bfloat16* Wsb  = (__hip_bfloat16*)(w + 3014656);
    __hip_bfloat16* Web  = (__hip_bfloat16*)(w + 3342336);
    __hip_bfloat16* Gb   = (__hip_bfloat16*)(w + 5505024);
    // total 9729024 bytes

    hipLaunchKernelGGL(kc_pad_bf16, dim3((JJ * KP + 255) / 256), dim3(256), 0, stream,
                       W_sent, Wsb, JJ, DD, KP);
    hipLaunchKernelGGL(kc_pad_bf16, dim3((JJ * 2112 + 255) / 256), dim3(256), 0, stream,
                       W_emb, Web, JJ, VGG, 2112);
    hipLaunchKernelGGL(kc_pad_bf16, dim3((NII * 2112 + 255) / 256), dim3(256), 0, stream,
                       guide, Gb, NII, VGG, 2112);
    hipLaunchKernelGGL(k0_valid, dim3(BB / 256), dim3(256), 0, stream,
                       labels, valid, nonzero);
    hipLaunchKernelGGL(k1_femb_mfma, dim3(16, JJ / 64), dim3(256), 0, stream,
                       Gb, Web, b_emb, femb);
    hipLaunchKernelGGL(k2_scores_mfma, dim3((BB * SS) / 64), dim3(256), 0, stream,
                       context, Wsb, b_sent, w_fc, b_fc, femb, ann, b_emb, valid, scores);
    hipLaunchKernelGGL(k3_out, dim3((BB + 2) / 3), dim3(256), 0, stream,
                       scores, nonzero, embedded, out);
}